// Round 2
// baseline (48.713 us; speedup 1.0000x reference)
//
#include <hip/hip_runtime.h>

// log sigma_{63,64} of exp(x) along classes: x (2048,10000) f32 -> out (2,2048) f32.
// Linear-domain with global exponential tilt tau (flattens every level's profile),
// leaf polys (157 classes, deg<=16) per lane, 6-level LDS conv merge tree.

#define NS 2048
#define NC 10000
#define K 64
#define KDEG 64
#define NCO 65
#define DLEAF 16         // leaf truncation degree (contrib beyond ~ e^-36)
#define GPS 64
#define SPB 2
#define BLOCK (GPS * SPB)
#define STRIDE 76        // [4 pad][65 coeffs][7 pad], 16B-aligned rows
#define BPAD 4
#define NTILE 17

template<int T, int DIN>
__device__ __forceinline__ void merge_level(float (&poly)[GPS][STRIDE], int l) {
  constexpr int NT = (NTILE + T - 1) / T;
  const int mg = l / T;
  const int r  = l % T;
  const float* A = poly[mg * T];
  const float* B = poly[mg * T + (T >> 1)];
  float acc[NT][4];
#pragma unroll
  for (int u = 0; u < NT; ++u) {
    acc[u][0] = 0.f; acc[u][1] = 0.f; acc[u][2] = 0.f; acc[u][3] = 0.f;
    const int tt = r + u * T;
    if (tt < NTILE) {
      const int j0 = tt * 4;
      if (j0 <= 2 * DIN + 3) {               // outputs beyond 2*DIN are exactly 0
        const int imax = (j0 + 3 < DIN) ? (j0 + 3) : DIN;
        // sliding window b_q = B[j0+q-i]; pads + stored zeros handle edges
        float b0 = B[BPAD + j0 + 0];
        float b1 = B[BPAD + j0 + 1];
        float b2 = B[BPAD + j0 + 2];
        float b3 = B[BPAD + j0 + 3];
        for (int i = 0; i <= imax; ++i) {
          const float av = A[BPAD + i];
          acc[u][0] = fmaf(av, b0, acc[u][0]);
          acc[u][1] = fmaf(av, b1, acc[u][1]);
          acc[u][2] = fmaf(av, b2, acc[u][2]);
          acc[u][3] = fmaf(av, b3, acc[u][3]);
          b3 = b2; b2 = b1; b1 = b0;
          b0 = B[BPAD + j0 - i - 1];         // index >= 0 via lower pad
        }
      }
    }
  }
  __syncthreads();                            // all reads done before writes
#pragma unroll
  for (int u = 0; u < NT; ++u) {
    const int tt = r + u * T;
    if (tt < NTILE) {
      const int j0 = tt * 4;
      float* W = const_cast<float*>(A);
#pragma unroll
      for (int q = 0; q < 4; ++q)
        if (j0 + q < NCO) W[BPAD + j0 + q] = acc[u][q];
    }
  }
  __syncthreads();
}

__global__ __launch_bounds__(BLOCK, 2)
void logesp_kernel(const float* __restrict__ x, float* __restrict__ out) {
  __shared__ float poly[SPB][GPS][STRIDE];
  __shared__ float scales[SPB][GPS];

  const int t   = threadIdx.x;
  const int smp = t >> 6;
  const int l   = t & 63;
  const int s   = blockIdx.x * SPB + smp;

  // ---- phase 1: leaf ESP over interleaved float4 chunks, deg <= 16 ----
  float c[DLEAF + 1];
  c[0] = 1.0f;
#pragma unroll
  for (int j = 1; j <= DLEAF; ++j) c[j] = 0.0f;
  float S  = 0.0f;      // accumulated log-scale
  float cb = 1.0f;      // growth bound on max coefficient
  float sw = 0.0f;      // sum of weights (for tilt)

  const float* xs = x + (size_t)s * NC;
  const float4* xv = (const float4*)xs;       // 9984 = 39*64*4 via float4
  for (int i = 0; i < 39; ++i) {
    const float4 v = xv[l + i * 64];
#pragma unroll
    for (int cc = 0; cc < 4; ++cc) {
      const float xval = (cc == 0) ? v.x : (cc == 1) ? v.y : (cc == 2) ? v.z : v.w;
      const float w = __expf(xval);
      sw += w;
#pragma unroll
      for (int j = DLEAF; j >= 1; --j) c[j] = fmaf(w, c[j - 1], c[j]);
      cb = fmaf(w, cb, cb);
    }
    if (__any(cb > 1e18f)) {                  // wave-uniform renormalize
      float m = c[0];
#pragma unroll
      for (int j = 1; j <= DLEAF; ++j) m = fmaxf(m, c[j]);
      const float inv = 1.0f / m;
#pragma unroll
      for (int j = 0; j <= DLEAF; ++j) c[j] *= inv;
      S += __logf(m);
      cb = 1.0f;
    }
  }
  if (l < 16) {                               // tail classes 9984..9999
    const float w = __expf(xs[9984 + l]);
    sw += w;
#pragma unroll
    for (int j = DLEAF; j >= 1; --j) c[j] = fmaf(w, c[j - 1], c[j]);
  }

  // ---- tilt: tau = ln(wbar * (NC-K)/K), uniform per sample ----
  float tot = sw;
#pragma unroll
  for (int msk = 1; msk < 64; msk <<= 1) tot += __shfl_xor(tot, msk);
  const float wbar = tot * (1.0f / (float)NC);
  const float tau  = __logf(wbar * ((float)(NC - K) / (float)K));

  // ---- leaf store: tilted, normalized ----
  {
    float tv[DLEAF + 1];
    float mx = 0.0f;
#pragma unroll
    for (int j = 0; j <= DLEAF; ++j) {
      tv[j] = c[j] * __expf((8.0f - (float)j) * tau);   // centered tilt, stays normal
      mx = fmaxf(mx, tv[j]);
    }
    const float inv = 1.0f / mx;
    S += __logf(mx) - 8.0f * tau;
    float* row = poly[smp][l];
#pragma unroll
    for (int p = 0; p < BPAD; ++p) row[p] = 0.0f;
#pragma unroll
    for (int j = 0; j <= DLEAF; ++j) row[BPAD + j] = tv[j] * inv;
#pragma unroll
    for (int j = DLEAF + 1; j < NCO; ++j) row[BPAD + j] = 0.0f;
#pragma unroll
    for (int p = BPAD + NCO; p < STRIDE; ++p) row[p] = 0.0f;
    scales[smp][l] = S;
  }
  __syncthreads();

  // ---- phase 2: merge tree (pure convolutions; tilt makes f32 range safe) ----
  merge_level<2, 16>(poly[smp], l);
  merge_level<4, 32>(poly[smp], l);
  merge_level<8, 64>(poly[smp], l);
  merge_level<16, 64>(poly[smp], l);
  merge_level<32, 64>(poly[smp], l);
  merge_level<64, 64>(poly[smp], l);

  // ---- phase 3: output ----
  if (l == 0) {
    float Ssum = 0.0f;
    for (int g = 0; g < GPS; ++g) Ssum += scales[smp][g];
    const float c63 = poly[smp][0][BPAD + 63];
    const float c64 = poly[smp][0][BPAD + 64];
    out[s]      = __logf(c63) + Ssum + 63.0f * tau;
    out[NS + s] = __logf(c64) + Ssum + 64.0f * tau;
  }
}

extern "C" void kernel_launch(void* const* d_in, const int* in_sizes, int n_in,
                              void* d_out, int out_size, void* d_ws, size_t ws_size,
                              hipStream_t stream) {
  const float* x = (const float*)d_in[0];
  float* out = (float*)d_out;
  (void)in_sizes; (void)n_in; (void)d_ws; (void)ws_size; (void)out_size;
  logesp_kernel<<<NS / SPB, BLOCK, 0, stream>>>(x, out);
}

// Round 3
// 48.012 us; speedup vs baseline: 1.0146x; 1.0146x over previous
//
#include <hip/hip_runtime.h>

// log sigma_{63,64} of exp(x) along classes: x (2048,10000) f32 -> out (2,2048) f32.
// Per sample: 128 register-resident leaf polys (deg<=12) with global exponential
// tilt tau; L1 merge via shuffles; L2..L6 LDS conv merges (float4-blocked, per-merge
// max-normalization with exact log bookkeeping); final level emits only deg 63,64.

#define NS 2048
#define NC 10000
#define KSEL 64
#define DLEAF 12
#define NCL (DLEAF + 1)     // 13 leaf coeffs

#define STR_M1 36           // [4 pad | 25 coeffs | pad]  deg<=24
#define STR_M2 56           // [4 pad | 49 coeffs | 3 ]   deg<=48
#define STR_M3 72           // [4 pad | 65 coeffs | 3 ]   deg<=64

__device__ __forceinline__ float4 ld4(const float* p) { return *(const float4*)p; }

// Merge level: 128/T merges, T lanes each. Merge m: A=inE[m], B=inO[m],
// writes (m&1 ? outO : outE)[m>>1], max-normalized; log(max) accumulated in
// scLog[m] (single writer r==0, barriers between levels).
// DIN % 4 == 0 required (guarantees B reads stay within [ -4, DIN+3 ]).
template<int T, int DIN, int DOUT>
__device__ __forceinline__ void merge_lvl(const float* __restrict__ inE,
                                          const float* __restrict__ inO,
                                          int strideIn,
                                          float* __restrict__ outE,
                                          float* __restrict__ outO,
                                          int strideOut,
                                          float* __restrict__ scLog, int t) {
  constexpr int NTILE = (DOUT + 4) / 4;          // ceil((DOUT+1)/4)
  constexpr int NT = (NTILE + T - 1) / T;
  const int m = t / T;
  const int r = t % T;
  const float* A = inE + m * strideIn + 4;
  const float* B = inO + m * strideIn + 4;
  float* outRow = ((m & 1) ? outO : outE) + (m >> 1) * strideOut + 4;

  float acc[NT][4];
#pragma unroll
  for (int u = 0; u < NT; ++u) {
    acc[u][0] = acc[u][1] = acc[u][2] = acc[u][3] = 0.f;
    const int tt = r + u * T;
    if (tt < NTILE) {
      const int j0 = 4 * tt;
      const int ilo = (j0 > DIN) ? (j0 - DIN) : 0;          // == 0 mod 4
      const int imax = (j0 + 3 < DIN) ? (j0 + 3) : DIN;
      for (int i0 = ilo; i0 <= imax; i0 += 4) {
        const float4 a4 = ld4(A + i0);
        const float4 bl = ld4(B + j0 - i0 - 4);             // >= -4: pad zeros
        const float4 bh = ld4(B + j0 - i0);
        acc[u][0] = fmaf(a4.x, bh.x, acc[u][0]);
        acc[u][1] = fmaf(a4.x, bh.y, acc[u][1]);
        acc[u][2] = fmaf(a4.x, bh.z, acc[u][2]);
        acc[u][3] = fmaf(a4.x, bh.w, acc[u][3]);
        acc[u][0] = fmaf(a4.y, bl.w, acc[u][0]);
        acc[u][1] = fmaf(a4.y, bh.x, acc[u][1]);
        acc[u][2] = fmaf(a4.y, bh.y, acc[u][2]);
        acc[u][3] = fmaf(a4.y, bh.z, acc[u][3]);
        acc[u][0] = fmaf(a4.z, bl.z, acc[u][0]);
        acc[u][1] = fmaf(a4.z, bl.w, acc[u][1]);
        acc[u][2] = fmaf(a4.z, bh.x, acc[u][2]);
        acc[u][3] = fmaf(a4.z, bh.y, acc[u][3]);
        acc[u][0] = fmaf(a4.w, bl.y, acc[u][0]);
        acc[u][1] = fmaf(a4.w, bl.z, acc[u][1]);
        acc[u][2] = fmaf(a4.w, bl.w, acc[u][2]);
        acc[u][3] = fmaf(a4.w, bh.x, acc[u][3]);
      }
    }
  }

  // per-merge max-normalization (keeps magnitudes ~1 through 7 conv levels)
  float mx = 0.f;
#pragma unroll
  for (int u = 0; u < NT; ++u) {
    mx = fmaxf(mx, fmaxf(fmaxf(acc[u][0], acc[u][1]), fmaxf(acc[u][2], acc[u][3])));
  }
#pragma unroll
  for (int msk = 1; msk < T; msk <<= 1) mx = fmaxf(mx, __shfl_xor(mx, msk));
  const float inv = 1.f / mx;

#pragma unroll
  for (int u = 0; u < NT; ++u) {
    const int tt = r + u * T;
    if (tt < NTILE)
      *(float4*)(outRow + 4 * tt) =
          make_float4(acc[u][0] * inv, acc[u][1] * inv, acc[u][2] * inv, acc[u][3] * inv);
  }
  if (r == 0) {
    *(float4*)(outRow - 4) = make_float4(0.f, 0.f, 0.f, 0.f);   // BPAD zeros
    scLog[m] += __logf(mx);                                      // single writer
  }
}

__global__ __launch_bounds__(128, 4)
void logesp_kernel(const float* __restrict__ x, float* __restrict__ out) {
  // Region A: M1 (64 rows x 36) = 2304 f; reused by M3 chain (30 rows x 72 = 2160 f)
  // Region B: M2 (32 rows x 56) = 1792 f
  __shared__ float RA[2304];
  __shared__ float RB[1792];
  __shared__ float red[4];      // [0,1] = per-wave sum(w); [2,3] = per-wave sum(S)
  __shared__ float scLog[32];   // per-merge normalization logs (accumulated)

  const int t = threadIdx.x;
  const int s = blockIdx.x;

  // ---- phase 1: leaf ESP (deg<=12) over interleaved float4 chunks ----
  float c[NCL];
  c[0] = 1.f;
#pragma unroll
  for (int j = 1; j < NCL; ++j) c[j] = 0.f;
  float S = 0.f, cb = 1.f, sw = 0.f;

  const float4* xv = (const float4*)(x + (size_t)s * NC);   // 2500 float4 per sample
  for (int it = 0; it < 19; ++it) {                          // 19*128 = 2432
    const float4 v = xv[t + it * 128];
#pragma unroll
    for (int cc = 0; cc < 4; ++cc) {
      const float xval = (cc == 0) ? v.x : (cc == 1) ? v.y : (cc == 2) ? v.z : v.w;
      const float w = __expf(xval);
      sw += w;
#pragma unroll
      for (int j = DLEAF; j >= 1; --j) c[j] = fmaf(w, c[j - 1], c[j]);
      cb = fmaf(w, cb, cb);                                  // bound *= (1+w)
    }
    if (__any(cb > 1e18f)) {                                 // wave-uniform renorm
      float mx = c[0];
#pragma unroll
      for (int j = 1; j < NCL; ++j) mx = fmaxf(mx, c[j]);
      const float inv = 1.f / mx;
#pragma unroll
      for (int j = 0; j < NCL; ++j) c[j] *= inv;
      S += __logf(mx);
      cb = 1.f;
    }
  }
  if (t < 68) {                                              // tail: float4 2432..2499
    const float4 v = xv[2432 + t];
#pragma unroll
    for (int cc = 0; cc < 4; ++cc) {
      const float xval = (cc == 0) ? v.x : (cc == 1) ? v.y : (cc == 2) ? v.z : v.w;
      const float w = __expf(xval);
      sw += w;
#pragma unroll
      for (int j = DLEAF; j >= 1; --j) c[j] = fmaf(w, c[j - 1], c[j]);
    }
  }

  // ---- tilt tau = ln(wbar * (NC-K)/K), shared across the sample ----
#pragma unroll
  for (int msk = 1; msk < 64; msk <<= 1) sw += __shfl_xor(sw, msk);
  if ((t & 63) == 0) red[t >> 6] = sw;
  if (t < 32) scLog[t] = 0.f;
  __syncthreads();
  const float wsum = red[0] + red[1];
  const float tau = __logf(wsum * (1.f / (float)NC) * ((float)(NC - KSEL) / (float)KSEL));

  // ---- tilt + per-leaf max-normalize (in registers) ----
  {
    const float f = __expf(-tau);
    float p = 1.f, mx = 0.f;
#pragma unroll
    for (int j = 0; j < NCL; ++j) { c[j] *= p; p *= f; mx = fmaxf(mx, c[j]); }
    const float inv = 1.f / mx;
#pragma unroll
    for (int j = 0; j < NCL; ++j) c[j] *= inv;
    S += __logf(mx);
  }
  {
    float Sr = S;
#pragma unroll
    for (int msk = 1; msk < 64; msk <<= 1) Sr += __shfl_xor(Sr, msk);
    if ((t & 63) == 0) red[2 + (t >> 6)] = Sr;
  }

  // ---- L1: register conv via shuffle (deg 12+12 -> 24) ----
  float q[NCL];
#pragma unroll
  for (int j = 0; j < NCL; ++j) q[j] = __shfl_xor(c[j], 1);

  float* M1E = RA;
  float* M1O = RA + 1152;
  {
    float* row = (((t >> 1) & 1) ? M1O : M1E) + (t >> 2) * STR_M1 + 4;
    if ((t & 1) == 0) {           // even degrees 0..24
#pragma unroll
      for (int u = 0; u <= 12; ++u) {
        float a = 0.f;
#pragma unroll
        for (int i = 0; i <= DLEAF; ++i) {
          const int k = 2 * u - i;
          if (k >= 0 && k <= DLEAF) a = fmaf(c[i], q[k], a);
        }
        row[2 * u] = a;
      }
      row[26] = 0.f;
      *(float4*)(row - 4) = make_float4(0.f, 0.f, 0.f, 0.f);
    } else {                      // odd degrees 1..23
#pragma unroll
      for (int u = 0; u < 12; ++u) {
        float a = 0.f;
#pragma unroll
        for (int i = 0; i <= DLEAF; ++i) {
          const int k = 2 * u + 1 - i;
          if (k >= 0 && k <= DLEAF) a = fmaf(c[i], q[k], a);
        }
        row[2 * u + 1] = a;
      }
      row[25] = 0.f;
      row[27] = 0.f;
    }
  }
  __syncthreads();

  // ---- L2..L6: LDS merge tree ----
  float* M2E = RB;
  float* M2O = RB + 896;
  merge_lvl<4, 24, 48>(M1E, M1O, STR_M1, M2E, M2O, STR_M2, scLog, t);
  __syncthreads();
  float* M3aE = RA;
  float* M3aO = RA + 576;
  merge_lvl<8, 48, 64>(M2E, M2O, STR_M2, M3aE, M3aO, STR_M3, scLog, t);
  __syncthreads();
  float* M3bE = RA + 1152;
  float* M3bO = RA + 1440;
  merge_lvl<16, 64, 64>(M3aE, M3aO, STR_M3, M3bE, M3bO, STR_M3, scLog, t);
  __syncthreads();
  float* M3cE = RA + 1728;
  float* M3cO = RA + 1872;
  merge_lvl<32, 64, 64>(M3bE, M3bO, STR_M3, M3cE, M3cO, STR_M3, scLog, t);
  __syncthreads();
  float* M3dE = RA + 2016;
  float* M3dO = RA + 2088;
  merge_lvl<64, 64, 64>(M3cE, M3cO, STR_M3, M3dE, M3dO, STR_M3, scLog, t);
  __syncthreads();

  // ---- L7: only degrees 63,64 of the final merge ----
  if (t < 64) {
    const float* A = M3dE + 4;
    const float* B = M3dO + 4;
    const float a = A[t];
    float v63 = a * B[63 - t];
    float v64 = a * B[64 - t];
    float e = (t < 32) ? scLog[t] : 0.f;
#pragma unroll
    for (int msk = 1; msk < 64; msk <<= 1) {
      v63 += __shfl_xor(v63, msk);
      v64 += __shfl_xor(v64, msk);
      e   += __shfl_xor(e, msk);
    }
    if (t == 0) {
      v64 = fmaf(A[64], B[0], v64);
      const float Ssum = red[2] + red[3] + e;
      out[s]      = __logf(v63) + Ssum + 63.f * tau;
      out[NS + s] = __logf(v64) + Ssum + 64.f * tau;
    }
  }
}

extern "C" void kernel_launch(void* const* d_in, const int* in_sizes, int n_in,
                              void* d_out, int out_size, void* d_ws, size_t ws_size,
                              hipStream_t stream) {
  const float* x = (const float*)d_in[0];
  float* out = (float*)d_out;
  (void)in_sizes; (void)n_in; (void)d_ws; (void)ws_size; (void)out_size;
  logesp_kernel<<<NS, 128, 0, stream>>>(x, out);
}

// Round 4
// 40.786 us; speedup vs baseline: 1.1944x; 1.1772x over previous
//
#include <hip/hip_runtime.h>

// log sigma_{63,64} of exp(x) along classes: x (2048,10000) f32 -> out (2,2048) f32.
// 256 threads/sample. Global exponential tilt tau flattens every level's profile.
// 256 register leaves (deg<=6) -> RL1/RL2 shuffle merges (deg<=7, <=11, registers)
// -> L3/L4 tile-conv in LDS (W3=16, W4=20) -> L5/L6/L7 broadcast-conv in LDS
// (W5=32, W6=48, W7=65) -> final degrees 63,64. Staircase truncation: each level
// keeps ~j* + margin; per-merge max-normalization logged in scLog.

#define NS 2048
#define NC 10000
#define KSEL 64

__device__ __forceinline__ float4 ld4(const float* p) { return *(const float4*)p; }

__global__ __launch_bounds__(256, 8)
void logesp_kernel(const float* __restrict__ x, float* __restrict__ out) {
  // Region A: W2 (64 rows x 20 = 1280) -> W4 (16 x 52 = 832) -> W6 (4 x 116 = 464)
  // Region B: W3 (32 rows x 28 = 896) -> W5 (8 x 84 = 672) -> W7 (2 x 76 = 152)
  __shared__ float RA[1280];
  __shared__ float RB[896];
  __shared__ float scLog[32];   // per-merge normalization logs (accumulated +=)
  __shared__ float red[8];      // [0..3] per-wave sum(w); [4..7] per-wave sum(S)

  const int t  = threadIdx.x;
  const int wv = t >> 6;        // wave id 0..3
  const int s  = blockIdx.x;

  // ---------- phase 1: leaf ESP, deg <= 6, untilted (provably f32-safe) ----------
  float c0 = 1.f, c1 = 0.f, c2 = 0.f, c3 = 0.f, c4 = 0.f, c5 = 0.f, c6 = 0.f;
  float sw = 0.f;
  const float4* xv = (const float4*)(x + (size_t)s * NC);   // 2500 float4

#pragma unroll
  for (int it = 0; it < 9; ++it) {                          // 9*256 = 2304 chunks
    const float4 v = xv[t + it * 256];
#pragma unroll
    for (int q = 0; q < 4; ++q) {
      const float xval = q == 0 ? v.x : q == 1 ? v.y : q == 2 ? v.z : v.w;
      const float wgt = __expf(xval);
      sw += wgt;
      c6 = fmaf(wgt, c5, c6);
      c5 = fmaf(wgt, c4, c5);
      c4 = fmaf(wgt, c3, c4);
      c3 = fmaf(wgt, c2, c3);
      c2 = fmaf(wgt, c1, c2);
      c1 = fmaf(wgt, c0, c1);   // c0 stays 1
    }
  }
  if (t < 196) {                                            // tail chunks 2304..2499
    const float4 v = xv[2304 + t];
#pragma unroll
    for (int q = 0; q < 4; ++q) {
      const float xval = q == 0 ? v.x : q == 1 ? v.y : q == 2 ? v.z : v.w;
      const float wgt = __expf(xval);
      sw += wgt;
      c6 = fmaf(wgt, c5, c6);
      c5 = fmaf(wgt, c4, c5);
      c4 = fmaf(wgt, c3, c4);
      c3 = fmaf(wgt, c2, c3);
      c2 = fmaf(wgt, c1, c2);
      c1 = fmaf(wgt, c0, c1);
    }
  }

  // ---------- tilt tau = ln(wbar*(NC-K)/K), uniform per sample ----------
#pragma unroll
  for (int m = 1; m < 64; m <<= 1) sw += __shfl_xor(sw, m);
  if ((t & 63) == 0) red[wv] = sw;
  if (t < 32) scLog[t] = 0.f;
  __syncthreads();
  const float wsum = red[0] + red[1] + red[2] + red[3];
  const float tau = __logf(wsum * ((float)(NC - KSEL) / ((float)KSEL * (float)NC)));

  // tilt + per-leaf max-normalize (registers); S = log scale
  {
    const float f1 = __expf(-tau);
    const float f2 = f1 * f1, f3 = f2 * f1, f4v = f2 * f2, f5 = f4v * f1, f6 = f4v * f2;
    c1 *= f1; c2 *= f2; c3 *= f3; c4 *= f4v; c5 *= f5; c6 *= f6;
  }
  float mx = fmaxf(fmaxf(fmaxf(c0, c1), fmaxf(c2, c3)), fmaxf(fmaxf(c4, c5), c6));
  {
    const float inv = 1.f / mx;
    c0 *= inv; c1 *= inv; c2 *= inv; c3 *= inv; c4 *= inv; c5 *= inv; c6 *= inv;
  }
  {
    float Sr = __logf(mx);
#pragma unroll
    for (int m = 1; m < 64; m <<= 1) Sr += __shfl_xor(Sr, m);
    if ((t & 63) == 0) red[4 + wv] = Sr;
  }

  // ---------- RL1: pair merge via shfl (78 classes, keep deg <= 7) ----------
  const float q0 = __shfl_xor(c0, 1), q1 = __shfl_xor(c1, 1), q2 = __shfl_xor(c2, 1),
              q3 = __shfl_xor(c3, 1), q4 = __shfl_xor(c4, 1), q5 = __shfl_xor(c5, 1),
              q6 = __shfl_xor(c6, 1);
  float e0 = c0 * q0;
  float e1 = fmaf(c1, q0, c0 * q1);
  float e2 = fmaf(c2, q0, fmaf(c1, q1, c0 * q2));
  float e3 = fmaf(c3, q0, fmaf(c2, q1, fmaf(c1, q2, c0 * q3)));
  float e4 = fmaf(c4, q0, fmaf(c3, q1, fmaf(c2, q2, fmaf(c1, q3, c0 * q4))));
  float e5 = fmaf(c5, q0, fmaf(c4, q1, fmaf(c3, q2, fmaf(c2, q3, fmaf(c1, q4, c0 * q5)))));
  float e6 = fmaf(c6, q0, fmaf(c5, q1, fmaf(c4, q2, fmaf(c3, q3, fmaf(c2, q4, fmaf(c1, q5, c0 * q6))))));
  float e7 = fmaf(c6, q1, fmaf(c5, q2, fmaf(c4, q3, fmaf(c3, q4, fmaf(c2, q5, c1 * q6)))));

  // ---------- RL2: 4-leaf merge via shfl (156 classes, keep deg <= 11) ----------
  const float f0 = __shfl_xor(e0, 2), f1 = __shfl_xor(e1, 2), f2 = __shfl_xor(e2, 2),
              f3 = __shfl_xor(e3, 2), f4 = __shfl_xor(e4, 2), f5 = __shfl_xor(e5, 2),
              f6 = __shfl_xor(e6, 2), f7 = __shfl_xor(e7, 2);
  const float g0 = e0 * f0;
  const float g1 = fmaf(e1, f0, e0 * f1);
  const float g2 = fmaf(e2, f0, fmaf(e1, f1, e0 * f2));
  const float g3 = fmaf(e3, f0, fmaf(e2, f1, fmaf(e1, f2, e0 * f3)));
  const float g4 = fmaf(e4, f0, fmaf(e3, f1, fmaf(e2, f2, fmaf(e1, f3, e0 * f4))));
  const float g5 = fmaf(e5, f0, fmaf(e4, f1, fmaf(e3, f2, fmaf(e2, f3, fmaf(e1, f4, e0 * f5)))));
  const float g6 = fmaf(e6, f0, fmaf(e5, f1, fmaf(e4, f2, fmaf(e3, f3, fmaf(e2, f4, fmaf(e1, f5, e0 * f6))))));
  const float g7 = fmaf(e7, f0, fmaf(e6, f1, fmaf(e5, f2, fmaf(e4, f3, fmaf(e3, f4, fmaf(e2, f5, fmaf(e1, f6, e0 * f7)))))));
  const float g8 = fmaf(e7, f1, fmaf(e6, f2, fmaf(e5, f3, fmaf(e4, f4, fmaf(e3, f5, fmaf(e2, f6, e1 * f7))))));
  const float g9 = fmaf(e7, f2, fmaf(e6, f3, fmaf(e5, f4, fmaf(e4, f5, fmaf(e3, f6, e2 * f7)))));
  const float g10 = fmaf(e7, f3, fmaf(e6, f4, fmaf(e5, f5, fmaf(e4, f6, e3 * f7))));
  const float g11 = fmaf(e7, f4, fmaf(e6, f5, fmaf(e5, f6, e4 * f7)));

  // store W2: 64 rows, stride 20 = [4 pad | 12 | 4 zeros]
  if ((t & 3) == 0) {
    float* row = RA + (t >> 2) * 20;
    *(float4*)(row)      = make_float4(0.f, 0.f, 0.f, 0.f);
    *(float4*)(row + 4)  = make_float4(g0, g1, g2, g3);
    *(float4*)(row + 8)  = make_float4(g4, g5, g6, g7);
    *(float4*)(row + 12) = make_float4(g8, g9, g10, g11);
    *(float4*)(row + 16) = make_float4(0.f, 0.f, 0.f, 0.f);
  }
  __syncthreads();

  // ---------- L3 (tile conv): 32 merges, T=8, DIN=12, keep 16 ----------
  {
    const int m = t >> 3, r = t & 7;
    const float* A = RA + (2 * m) * 20;
    const float* B = RA + (2 * m + 1) * 20;
    float a0 = 0.f, a1 = 0.f, a2 = 0.f, a3 = 0.f;
    if (r < 4) {
      const int j0 = 4 * r;
      const int imax = (j0 + 3 < 12) ? j0 + 3 : 12;
      for (int i0 = 0; i0 <= imax; i0 += 4) {
        const float4 a4 = ld4(A + 4 + i0);
        const float4 bl = ld4(B + j0 - i0);       // degrees j0-i0-4 .. j0-i0-1
        const float4 bh = ld4(B + 4 + j0 - i0);   // degrees j0-i0 .. j0-i0+3
        a0 = fmaf(a4.x, bh.x, a0); a1 = fmaf(a4.x, bh.y, a1); a2 = fmaf(a4.x, bh.z, a2); a3 = fmaf(a4.x, bh.w, a3);
        a0 = fmaf(a4.y, bl.w, a0); a1 = fmaf(a4.y, bh.x, a1); a2 = fmaf(a4.y, bh.y, a2); a3 = fmaf(a4.y, bh.z, a3);
        a0 = fmaf(a4.z, bl.z, a0); a1 = fmaf(a4.z, bl.w, a1); a2 = fmaf(a4.z, bh.x, a2); a3 = fmaf(a4.z, bh.y, a3);
        a0 = fmaf(a4.w, bl.y, a0); a1 = fmaf(a4.w, bl.z, a1); a2 = fmaf(a4.w, bl.w, a2); a3 = fmaf(a4.w, bh.x, a3);
      }
    }
    float m2 = fmaxf(fmaxf(a0, a1), fmaxf(a2, a3));
    m2 = fmaxf(m2, __shfl_xor(m2, 1)); m2 = fmaxf(m2, __shfl_xor(m2, 2)); m2 = fmaxf(m2, __shfl_xor(m2, 4));
    const float inv = 1.f / m2;
    float* o = RB + m * 28;                        // [4 pad | 16 | 4 zeros | 4 unused]
    if (r < 4) *(float4*)(o + 4 + 4 * r) = make_float4(a0 * inv, a1 * inv, a2 * inv, a3 * inv);
    if (r == 4) *(float4*)(o) = make_float4(0.f, 0.f, 0.f, 0.f);
    if (r == 5) *(float4*)(o + 20) = make_float4(0.f, 0.f, 0.f, 0.f);
    if (r == 0) scLog[m] += __logf(m2);
  }
  __syncthreads();

  // ---------- L4 (tile conv): 16 merges, T=16, DIN=16, keep 20 ----------
  {
    const int m = t >> 4, r = t & 15;
    const float* A = RB + (2 * m) * 28;
    const float* B = RB + (2 * m + 1) * 28;
    float a0 = 0.f, a1 = 0.f, a2 = 0.f, a3 = 0.f;
    if (r < 5) {
      const int j0 = 4 * r;
      const int imax = (j0 + 3 < 16) ? j0 + 3 : 16;
      for (int i0 = 0; i0 <= imax; i0 += 4) {
        const float4 a4 = ld4(A + 4 + i0);
        const float4 bl = ld4(B + j0 - i0);
        const float4 bh = ld4(B + 4 + j0 - i0);
        a0 = fmaf(a4.x, bh.x, a0); a1 = fmaf(a4.x, bh.y, a1); a2 = fmaf(a4.x, bh.z, a2); a3 = fmaf(a4.x, bh.w, a3);
        a0 = fmaf(a4.y, bl.w, a0); a1 = fmaf(a4.y, bh.x, a1); a2 = fmaf(a4.y, bh.y, a2); a3 = fmaf(a4.y, bh.z, a3);
        a0 = fmaf(a4.z, bl.z, a0); a1 = fmaf(a4.z, bl.w, a1); a2 = fmaf(a4.z, bh.x, a2); a3 = fmaf(a4.z, bh.y, a3);
        a0 = fmaf(a4.w, bl.y, a0); a1 = fmaf(a4.w, bl.z, a1); a2 = fmaf(a4.w, bl.w, a2); a3 = fmaf(a4.w, bh.x, a3);
      }
    }
    float m2 = fmaxf(fmaxf(a0, a1), fmaxf(a2, a3));
    m2 = fmaxf(m2, __shfl_xor(m2, 1)); m2 = fmaxf(m2, __shfl_xor(m2, 2));
    m2 = fmaxf(m2, __shfl_xor(m2, 4)); m2 = fmaxf(m2, __shfl_xor(m2, 8));
    const float inv = 1.f / m2;
    float* o = RA + m * 52;                        // [20 pad | 20 | 12 zeros]
    if (r < 5) *(float4*)(o + 20 + 4 * r) = make_float4(a0 * inv, a1 * inv, a2 * inv, a3 * inv);
    if (r >= 5 && r < 10) *(float4*)(o + 4 * (r - 5)) = make_float4(0.f, 0.f, 0.f, 0.f);
    if (r >= 10 && r < 13) *(float4*)(o + 40 + 4 * (r - 10)) = make_float4(0.f, 0.f, 0.f, 0.f);
    if (r == 0) scLog[m] += __logf(m2);
  }
  __syncthreads();

  // ---------- L5 (broadcast conv): 8 merges, 2/wave, DIN=20, keep 32 ----------
  {
    const int half = (t >> 5) & 1;
    const int m = 2 * wv + half;
    const int p = t & 31;
    const float* A = RA + (2 * m) * 52 + 20;
    const float* B = RA + (2 * m + 1) * 52 + 20;
    float acc = 0.f;
#pragma unroll
    for (int i0 = 0; i0 < 20; i0 += 4) {
      const float4 a4 = ld4(A + i0);
      acc = fmaf(a4.x, B[p - i0], acc);
      acc = fmaf(a4.y, B[p - i0 - 1], acc);
      acc = fmaf(a4.z, B[p - i0 - 2], acc);
      acc = fmaf(a4.w, B[p - i0 - 3], acc);
    }
    float m2 = acc;
    m2 = fmaxf(m2, __shfl_xor(m2, 1)); m2 = fmaxf(m2, __shfl_xor(m2, 2));
    m2 = fmaxf(m2, __shfl_xor(m2, 4)); m2 = fmaxf(m2, __shfl_xor(m2, 8));
    m2 = fmaxf(m2, __shfl_xor(m2, 16));
    const float inv = 1.f / m2;
    float* o = RB + m * 84;                        // [32 pad | 32 | 20 zeros]
    o[32 + p] = acc * inv;
    if (p < 8) *(float4*)(o + 4 * p) = make_float4(0.f, 0.f, 0.f, 0.f);
    if (p >= 8 && p < 13) *(float4*)(o + 64 + 4 * (p - 8)) = make_float4(0.f, 0.f, 0.f, 0.f);
    if (p == 0) scLog[m] += __logf(m2);
  }
  __syncthreads();

  // ---------- L6 (broadcast conv): 4 merges, 1/wave, DIN=32, keep 48 ----------
  {
    const int p = t & 63;
    const float* A = RB + (2 * wv) * 84 + 32;
    const float* B = RB + (2 * wv + 1) * 84 + 32;
    float acc = 0.f;
    if (p < 48) {
#pragma unroll
      for (int i0 = 0; i0 < 32; i0 += 4) {
        const float4 a4 = ld4(A + i0);
        acc = fmaf(a4.x, B[p - i0], acc);
        acc = fmaf(a4.y, B[p - i0 - 1], acc);
        acc = fmaf(a4.z, B[p - i0 - 2], acc);
        acc = fmaf(a4.w, B[p - i0 - 3], acc);
      }
    }
    float m2 = acc;
#pragma unroll
    for (int msk = 1; msk < 64; msk <<= 1) m2 = fmaxf(m2, __shfl_xor(m2, msk));
    const float inv = 1.f / m2;
    float* o = RA + wv * 116;                      // [48 pad | 48 | 20 zeros]
    if (p < 48) o[48 + p] = acc * inv;
    if (p >= 48 && p < 60) *(float4*)(o + 4 * (p - 48)) = make_float4(0.f, 0.f, 0.f, 0.f);
    if (p >= 60) *(float4*)(o + 96 + 4 * (p - 60)) = make_float4(0.f, 0.f, 0.f, 0.f);
    if (p == 59) *(float4*)(o + 112) = make_float4(0.f, 0.f, 0.f, 0.f);
    if (p == 0) scLog[wv] += __logf(m2);
  }
  __syncthreads();

  // ---------- L7 (broadcast conv): 2 merges on waves 0,1; DIN=48, keep 65 ----------
  if (t < 128) {
    const int p = t & 63;
    const float* A = RA + (2 * wv) * 116 + 48;
    const float* B = RA + (2 * wv + 1) * 116 + 48;
    float acc = 0.f;
#pragma unroll
    for (int i0 = 0; i0 < 48; i0 += 4) {
      const float4 a4 = ld4(A + i0);
      acc = fmaf(a4.x, B[p - i0], acc);
      acc = fmaf(a4.y, B[p - i0 - 1], acc);
      acc = fmaf(a4.z, B[p - i0 - 2], acc);
      acc = fmaf(a4.w, B[p - i0 - 3], acc);
    }
    // degree 64 cooperatively (top pads of B are zeros, so i<17 terms vanish)
    float c64 = (p < 48) ? A[p] * B[64 - p] : 0.f;
#pragma unroll
    for (int msk = 1; msk < 64; msk <<= 1) c64 += __shfl_xor(c64, msk);
    float m2 = fmaxf(acc, c64);
#pragma unroll
    for (int msk = 1; msk < 64; msk <<= 1) m2 = fmaxf(m2, __shfl_xor(m2, msk));
    const float inv = 1.f / m2;
    float* o = RB + wv * 76;                       // [4 pad | 65 | 7 unused]
    o[4 + p] = acc * inv;
    if (p == 0) { o[68] = c64 * inv; scLog[wv] += __logf(m2); }
    if (p == 1) *(float4*)(o) = make_float4(0.f, 0.f, 0.f, 0.f);
  }
  __syncthreads();

  // ---------- L8: final degrees 63, 64 + output ----------
  if (t < 64) {
    const float* A = RB + 4;
    const float* B = RB + 76 + 4;
    const float a = A[t];
    float v63 = a * B[63 - t];
    float v64 = a * B[64 - t];
    float ee = (t < 32) ? scLog[t] : 0.f;
#pragma unroll
    for (int msk = 1; msk < 64; msk <<= 1) {
      v63 += __shfl_xor(v63, msk);
      v64 += __shfl_xor(v64, msk);
      ee  += __shfl_xor(ee, msk);
    }
    if (t == 0) {
      v64 = fmaf(A[64], B[0], v64);
      const float Ssum = red[4] + red[5] + red[6] + red[7] + ee;
      out[s]      = __logf(v63) + Ssum + 63.f * tau;
      out[NS + s] = __logf(v64) + Ssum + 64.f * tau;
    }
  }
}

extern "C" void kernel_launch(void* const* d_in, const int* in_sizes, int n_in,
                              void* d_out, int out_size, void* d_ws, size_t ws_size,
                              hipStream_t stream) {
  const float* x = (const float*)d_in[0];
  float* out = (float*)d_out;
  (void)in_sizes; (void)n_in; (void)d_ws; (void)ws_size; (void)out_size;
  logesp_kernel<<<NS, 256, 0, stream>>>(x, out);
}

// Round 5
// 32.276 us; speedup vs baseline: 1.5093x; 1.2637x over previous
//
#include <hip/hip_runtime.h>

// log sigma_{63,64} of exp(x) along classes: x (2048,10000) f32 -> out (2,2048) f32.
// 256 threads/sample. Global exponential tilt tau flattens every level's profile.
// 256 register leaves (deg<=6) -> RL1/RL2 shuffle merges (deg<=7, <=11, registers)
// -> L3/L4 tile-conv in LDS (W3=16, W4=20) -> L5/L6/L7 broadcast-conv in LDS
// (W5=32, W6=48, W7=65) -> final degrees 63,64. Staircase truncation; per-merge
// max-normalization logged in scLog.
// Round 5 change: __launch_bounds__(256,4) (VGPR cap 128, was 64) — round 4's
// cap of 64 forced VGPR=32 with ~52 MB of scratch spill traffic per dispatch.

#define NS 2048
#define NC 10000
#define KSEL 64

__device__ __forceinline__ float4 ld4(const float* p) { return *(const float4*)p; }

__global__ __launch_bounds__(256, 4)
void logesp_kernel(const float* __restrict__ x, float* __restrict__ out) {
  // Region A: W2 (64 rows x 20 = 1280) -> W4 (16 x 52 = 832) -> W6 (4 x 116 = 464)
  // Region B: W3 (32 rows x 28 = 896) -> W5 (8 x 84 = 672) -> W7 (2 x 76 = 152)
  __shared__ float RA[1280];
  __shared__ float RB[896];
  __shared__ float scLog[32];   // per-merge normalization logs (accumulated +=)
  __shared__ float red[8];      // [0..3] per-wave sum(w); [4..7] per-wave sum(S)

  const int t  = threadIdx.x;
  const int wv = t >> 6;        // wave id 0..3
  const int s  = blockIdx.x;

  // ---------- phase 1: leaf ESP, deg <= 6, untilted (provably f32-safe) ----------
  float c0 = 1.f, c1 = 0.f, c2 = 0.f, c3 = 0.f, c4 = 0.f, c5 = 0.f, c6 = 0.f;
  float sw = 0.f;
  const float4* xv = (const float4*)(x + (size_t)s * NC);   // 2500 float4

#pragma unroll
  for (int it = 0; it < 9; ++it) {                          // 9*256 = 2304 chunks
    const float4 v = xv[t + it * 256];
#pragma unroll
    for (int q = 0; q < 4; ++q) {
      const float xval = q == 0 ? v.x : q == 1 ? v.y : q == 2 ? v.z : v.w;
      const float wgt = __expf(xval);
      sw += wgt;
      c6 = fmaf(wgt, c5, c6);
      c5 = fmaf(wgt, c4, c5);
      c4 = fmaf(wgt, c3, c4);
      c3 = fmaf(wgt, c2, c3);
      c2 = fmaf(wgt, c1, c2);
      c1 = fmaf(wgt, c0, c1);   // c0 stays 1
    }
  }
  if (t < 196) {                                            // tail chunks 2304..2499
    const float4 v = xv[2304 + t];
#pragma unroll
    for (int q = 0; q < 4; ++q) {
      const float xval = q == 0 ? v.x : q == 1 ? v.y : q == 2 ? v.z : v.w;
      const float wgt = __expf(xval);
      sw += wgt;
      c6 = fmaf(wgt, c5, c6);
      c5 = fmaf(wgt, c4, c5);
      c4 = fmaf(wgt, c3, c4);
      c3 = fmaf(wgt, c2, c3);
      c2 = fmaf(wgt, c1, c2);
      c1 = fmaf(wgt, c0, c1);
    }
  }

  // ---------- tilt tau = ln(wbar*(NC-K)/K), uniform per sample ----------
#pragma unroll
  for (int m = 1; m < 64; m <<= 1) sw += __shfl_xor(sw, m);
  if ((t & 63) == 0) red[wv] = sw;
  if (t < 32) scLog[t] = 0.f;
  __syncthreads();
  const float wsum = red[0] + red[1] + red[2] + red[3];
  const float tau = __logf(wsum * ((float)(NC - KSEL) / ((float)KSEL * (float)NC)));

  // tilt + per-leaf max-normalize (registers); S = log scale
  {
    const float f1 = __expf(-tau);
    const float f2 = f1 * f1, f3 = f2 * f1, f4v = f2 * f2, f5 = f4v * f1, f6 = f4v * f2;
    c1 *= f1; c2 *= f2; c3 *= f3; c4 *= f4v; c5 *= f5; c6 *= f6;
  }
  float mx = fmaxf(fmaxf(fmaxf(c0, c1), fmaxf(c2, c3)), fmaxf(fmaxf(c4, c5), c6));
  {
    const float inv = 1.f / mx;
    c0 *= inv; c1 *= inv; c2 *= inv; c3 *= inv; c4 *= inv; c5 *= inv; c6 *= inv;
  }
  {
    float Sr = __logf(mx);
#pragma unroll
    for (int m = 1; m < 64; m <<= 1) Sr += __shfl_xor(Sr, m);
    if ((t & 63) == 0) red[4 + wv] = Sr;
  }

  // ---------- RL1: pair merge via shfl (78 classes, keep deg <= 7) ----------
  const float q0 = __shfl_xor(c0, 1), q1 = __shfl_xor(c1, 1), q2 = __shfl_xor(c2, 1),
              q3 = __shfl_xor(c3, 1), q4 = __shfl_xor(c4, 1), q5 = __shfl_xor(c5, 1),
              q6 = __shfl_xor(c6, 1);
  float e0 = c0 * q0;
  float e1 = fmaf(c1, q0, c0 * q1);
  float e2 = fmaf(c2, q0, fmaf(c1, q1, c0 * q2));
  float e3 = fmaf(c3, q0, fmaf(c2, q1, fmaf(c1, q2, c0 * q3)));
  float e4 = fmaf(c4, q0, fmaf(c3, q1, fmaf(c2, q2, fmaf(c1, q3, c0 * q4))));
  float e5 = fmaf(c5, q0, fmaf(c4, q1, fmaf(c3, q2, fmaf(c2, q3, fmaf(c1, q4, c0 * q5)))));
  float e6 = fmaf(c6, q0, fmaf(c5, q1, fmaf(c4, q2, fmaf(c3, q3, fmaf(c2, q4, fmaf(c1, q5, c0 * q6))))));
  float e7 = fmaf(c6, q1, fmaf(c5, q2, fmaf(c4, q3, fmaf(c3, q4, fmaf(c2, q5, c1 * q6)))));

  // ---------- RL2: 4-leaf merge via shfl (156 classes, keep deg <= 11) ----------
  const float f0 = __shfl_xor(e0, 2), f1 = __shfl_xor(e1, 2), f2 = __shfl_xor(e2, 2),
              f3 = __shfl_xor(e3, 2), f4 = __shfl_xor(e4, 2), f5 = __shfl_xor(e5, 2),
              f6 = __shfl_xor(e6, 2), f7 = __shfl_xor(e7, 2);
  const float g0 = e0 * f0;
  const float g1 = fmaf(e1, f0, e0 * f1);
  const float g2 = fmaf(e2, f0, fmaf(e1, f1, e0 * f2));
  const float g3 = fmaf(e3, f0, fmaf(e2, f1, fmaf(e1, f2, e0 * f3)));
  const float g4 = fmaf(e4, f0, fmaf(e3, f1, fmaf(e2, f2, fmaf(e1, f3, e0 * f4))));
  const float g5 = fmaf(e5, f0, fmaf(e4, f1, fmaf(e3, f2, fmaf(e2, f3, fmaf(e1, f4, e0 * f5)))));
  const float g6 = fmaf(e6, f0, fmaf(e5, f1, fmaf(e4, f2, fmaf(e3, f3, fmaf(e2, f4, fmaf(e1, f5, e0 * f6))))));
  const float g7 = fmaf(e7, f0, fmaf(e6, f1, fmaf(e5, f2, fmaf(e4, f3, fmaf(e3, f4, fmaf(e2, f5, fmaf(e1, f6, e0 * f7)))))));
  const float g8 = fmaf(e7, f1, fmaf(e6, f2, fmaf(e5, f3, fmaf(e4, f4, fmaf(e3, f5, fmaf(e2, f6, e1 * f7))))));
  const float g9 = fmaf(e7, f2, fmaf(e6, f3, fmaf(e5, f4, fmaf(e4, f5, fmaf(e3, f6, e2 * f7)))));
  const float g10 = fmaf(e7, f3, fmaf(e6, f4, fmaf(e5, f5, fmaf(e4, f6, e3 * f7))));
  const float g11 = fmaf(e7, f4, fmaf(e6, f5, fmaf(e5, f6, e4 * f7)));

  // store W2: 64 rows, stride 20 = [4 pad | 12 | 4 zeros]
  if ((t & 3) == 0) {
    float* row = RA + (t >> 2) * 20;
    *(float4*)(row)      = make_float4(0.f, 0.f, 0.f, 0.f);
    *(float4*)(row + 4)  = make_float4(g0, g1, g2, g3);
    *(float4*)(row + 8)  = make_float4(g4, g5, g6, g7);
    *(float4*)(row + 12) = make_float4(g8, g9, g10, g11);
    *(float4*)(row + 16) = make_float4(0.f, 0.f, 0.f, 0.f);
  }
  __syncthreads();

  // ---------- L3 (tile conv): 32 merges, T=8, DIN=12, keep 16 ----------
  {
    const int m = t >> 3, r = t & 7;
    const float* A = RA + (2 * m) * 20;
    const float* B = RA + (2 * m + 1) * 20;
    float a0 = 0.f, a1 = 0.f, a2 = 0.f, a3 = 0.f;
    if (r < 4) {
      const int j0 = 4 * r;
      const int imax = (j0 + 3 < 12) ? j0 + 3 : 12;
      for (int i0 = 0; i0 <= imax; i0 += 4) {
        const float4 a4 = ld4(A + 4 + i0);
        const float4 bl = ld4(B + j0 - i0);       // degrees j0-i0-4 .. j0-i0-1
        const float4 bh = ld4(B + 4 + j0 - i0);   // degrees j0-i0 .. j0-i0+3
        a0 = fmaf(a4.x, bh.x, a0); a1 = fmaf(a4.x, bh.y, a1); a2 = fmaf(a4.x, bh.z, a2); a3 = fmaf(a4.x, bh.w, a3);
        a0 = fmaf(a4.y, bl.w, a0); a1 = fmaf(a4.y, bh.x, a1); a2 = fmaf(a4.y, bh.y, a2); a3 = fmaf(a4.y, bh.z, a3);
        a0 = fmaf(a4.z, bl.z, a0); a1 = fmaf(a4.z, bl.w, a1); a2 = fmaf(a4.z, bh.x, a2); a3 = fmaf(a4.z, bh.y, a3);
        a0 = fmaf(a4.w, bl.y, a0); a1 = fmaf(a4.w, bl.z, a1); a2 = fmaf(a4.w, bl.w, a2); a3 = fmaf(a4.w, bh.x, a3);
      }
    }
    float m2 = fmaxf(fmaxf(a0, a1), fmaxf(a2, a3));
    m2 = fmaxf(m2, __shfl_xor(m2, 1)); m2 = fmaxf(m2, __shfl_xor(m2, 2)); m2 = fmaxf(m2, __shfl_xor(m2, 4));
    const float inv = 1.f / m2;
    float* o = RB + m * 28;                        // [4 pad | 16 | 4 zeros | 4 unused]
    if (r < 4) *(float4*)(o + 4 + 4 * r) = make_float4(a0 * inv, a1 * inv, a2 * inv, a3 * inv);
    if (r == 4) *(float4*)(o) = make_float4(0.f, 0.f, 0.f, 0.f);
    if (r == 5) *(float4*)(o + 20) = make_float4(0.f, 0.f, 0.f, 0.f);
    if (r == 0) scLog[m] += __logf(m2);
  }
  __syncthreads();

  // ---------- L4 (tile conv): 16 merges, T=16, DIN=16, keep 20 ----------
  {
    const int m = t >> 4, r = t & 15;
    const float* A = RB + (2 * m) * 28;
    const float* B = RB + (2 * m + 1) * 28;
    float a0 = 0.f, a1 = 0.f, a2 = 0.f, a3 = 0.f;
    if (r < 5) {
      const int j0 = 4 * r;
      const int imax = (j0 + 3 < 16) ? j0 + 3 : 16;
      for (int i0 = 0; i0 <= imax; i0 += 4) {
        const float4 a4 = ld4(A + 4 + i0);
        const float4 bl = ld4(B + j0 - i0);
        const float4 bh = ld4(B + 4 + j0 - i0);
        a0 = fmaf(a4.x, bh.x, a0); a1 = fmaf(a4.x, bh.y, a1); a2 = fmaf(a4.x, bh.z, a2); a3 = fmaf(a4.x, bh.w, a3);
        a0 = fmaf(a4.y, bl.w, a0); a1 = fmaf(a4.y, bh.x, a1); a2 = fmaf(a4.y, bh.y, a2); a3 = fmaf(a4.y, bh.z, a3);
        a0 = fmaf(a4.z, bl.z, a0); a1 = fmaf(a4.z, bl.w, a1); a2 = fmaf(a4.z, bh.x, a2); a3 = fmaf(a4.z, bh.y, a3);
        a0 = fmaf(a4.w, bl.y, a0); a1 = fmaf(a4.w, bl.z, a1); a2 = fmaf(a4.w, bl.w, a2); a3 = fmaf(a4.w, bh.x, a3);
      }
    }
    float m2 = fmaxf(fmaxf(a0, a1), fmaxf(a2, a3));
    m2 = fmaxf(m2, __shfl_xor(m2, 1)); m2 = fmaxf(m2, __shfl_xor(m2, 2));
    m2 = fmaxf(m2, __shfl_xor(m2, 4)); m2 = fmaxf(m2, __shfl_xor(m2, 8));
    const float inv = 1.f / m2;
    float* o = RA + m * 52;                        // [20 pad | 20 | 12 zeros]
    if (r < 5) *(float4*)(o + 20 + 4 * r) = make_float4(a0 * inv, a1 * inv, a2 * inv, a3 * inv);
    if (r >= 5 && r < 10) *(float4*)(o + 4 * (r - 5)) = make_float4(0.f, 0.f, 0.f, 0.f);
    if (r >= 10 && r < 13) *(float4*)(o + 40 + 4 * (r - 10)) = make_float4(0.f, 0.f, 0.f, 0.f);
    if (r == 0) scLog[m] += __logf(m2);
  }
  __syncthreads();

  // ---------- L5 (broadcast conv): 8 merges, 2/wave, DIN=20, keep 32 ----------
  {
    const int half = (t >> 5) & 1;
    const int m = 2 * wv + half;
    const int p = t & 31;
    const float* A = RA + (2 * m) * 52 + 20;
    const float* B = RA + (2 * m + 1) * 52 + 20;
    float acc = 0.f;
#pragma unroll
    for (int i0 = 0; i0 < 20; i0 += 4) {
      const float4 a4 = ld4(A + i0);
      acc = fmaf(a4.x, B[p - i0], acc);
      acc = fmaf(a4.y, B[p - i0 - 1], acc);
      acc = fmaf(a4.z, B[p - i0 - 2], acc);
      acc = fmaf(a4.w, B[p - i0 - 3], acc);
    }
    float m2 = acc;
    m2 = fmaxf(m2, __shfl_xor(m2, 1)); m2 = fmaxf(m2, __shfl_xor(m2, 2));
    m2 = fmaxf(m2, __shfl_xor(m2, 4)); m2 = fmaxf(m2, __shfl_xor(m2, 8));
    m2 = fmaxf(m2, __shfl_xor(m2, 16));
    const float inv = 1.f / m2;
    float* o = RB + m * 84;                        // [32 pad | 32 | 20 zeros]
    o[32 + p] = acc * inv;
    if (p < 8) *(float4*)(o + 4 * p) = make_float4(0.f, 0.f, 0.f, 0.f);
    if (p >= 8 && p < 13) *(float4*)(o + 64 + 4 * (p - 8)) = make_float4(0.f, 0.f, 0.f, 0.f);
    if (p == 0) scLog[m] += __logf(m2);
  }
  __syncthreads();

  // ---------- L6 (broadcast conv): 4 merges, 1/wave, DIN=32, keep 48 ----------
  {
    const int p = t & 63;
    const float* A = RB + (2 * wv) * 84 + 32;
    const float* B = RB + (2 * wv + 1) * 84 + 32;
    float acc = 0.f;
    if (p < 48) {
#pragma unroll
      for (int i0 = 0; i0 < 32; i0 += 4) {
        const float4 a4 = ld4(A + i0);
        acc = fmaf(a4.x, B[p - i0], acc);
        acc = fmaf(a4.y, B[p - i0 - 1], acc);
        acc = fmaf(a4.z, B[p - i0 - 2], acc);
        acc = fmaf(a4.w, B[p - i0 - 3], acc);
      }
    }
    float m2 = acc;
#pragma unroll
    for (int msk = 1; msk < 64; msk <<= 1) m2 = fmaxf(m2, __shfl_xor(m2, msk));
    const float inv = 1.f / m2;
    float* o = RA + wv * 116;                      // [48 pad | 48 | 20 zeros]
    if (p < 48) o[48 + p] = acc * inv;
    if (p >= 48 && p < 60) *(float4*)(o + 4 * (p - 48)) = make_float4(0.f, 0.f, 0.f, 0.f);
    if (p >= 60) *(float4*)(o + 96 + 4 * (p - 60)) = make_float4(0.f, 0.f, 0.f, 0.f);
    if (p == 59) *(float4*)(o + 112) = make_float4(0.f, 0.f, 0.f, 0.f);
    if (p == 0) scLog[wv] += __logf(m2);
  }
  __syncthreads();

  // ---------- L7 (broadcast conv): 2 merges on waves 0,1; DIN=48, keep 65 ----------
  if (t < 128) {
    const int p = t & 63;
    const float* A = RA + (2 * wv) * 116 + 48;
    const float* B = RA + (2 * wv + 1) * 116 + 48;
    float acc = 0.f;
#pragma unroll
    for (int i0 = 0; i0 < 48; i0 += 4) {
      const float4 a4 = ld4(A + i0);
      acc = fmaf(a4.x, B[p - i0], acc);
      acc = fmaf(a4.y, B[p - i0 - 1], acc);
      acc = fmaf(a4.z, B[p - i0 - 2], acc);
      acc = fmaf(a4.w, B[p - i0 - 3], acc);
    }
    // degree 64 cooperatively (top pads of B are zeros, so i<17 terms vanish)
    float c64 = (p < 48) ? A[p] * B[64 - p] : 0.f;
#pragma unroll
    for (int msk = 1; msk < 64; msk <<= 1) c64 += __shfl_xor(c64, msk);
    float m2 = fmaxf(acc, c64);
#pragma unroll
    for (int msk = 1; msk < 64; msk <<= 1) m2 = fmaxf(m2, __shfl_xor(m2, msk));
    const float inv = 1.f / m2;
    float* o = RB + wv * 76;                       // [4 pad | 65 | 7 unused]
    o[4 + p] = acc * inv;
    if (p == 0) { o[68] = c64 * inv; scLog[wv] += __logf(m2); }
    if (p == 1) *(float4*)(o) = make_float4(0.f, 0.f, 0.f, 0.f);
  }
  __syncthreads();

  // ---------- L8: final degrees 63, 64 + output ----------
  if (t < 64) {
    const float* A = RB + 4;
    const float* B = RB + 76 + 4;
    const float a = A[t];
    float v63 = a * B[63 - t];
    float v64 = a * B[64 - t];
    float ee = (t < 32) ? scLog[t] : 0.f;
#pragma unroll
    for (int msk = 1; msk < 64; msk <<= 1) {
      v63 += __shfl_xor(v63, msk);
      v64 += __shfl_xor(v64, msk);
      ee  += __shfl_xor(ee, msk);
    }
    if (t == 0) {
      v64 = fmaf(A[64], B[0], v64);
      const float Ssum = red[4] + red[5] + red[6] + red[7] + ee;
      out[s]      = __logf(v63) + Ssum + 63.f * tau;
      out[NS + s] = __logf(v64) + Ssum + 64.f * tau;
    }
  }
}

extern "C" void kernel_launch(void* const* d_in, const int* in_sizes, int n_in,
                              void* d_out, int out_size, void* d_ws, size_t ws_size,
                              hipStream_t stream) {
  const float* x = (const float*)d_in[0];
  float* out = (float*)d_out;
  (void)in_sizes; (void)n_in; (void)d_ws; (void)ws_size; (void)out_size;
  logesp_kernel<<<NS, 256, 0, stream>>>(x, out);
}